// Round 3
// baseline (80.525 us; speedup 1.0000x reference)
//
#include <hip/hip_runtime.h>

// AbstractRelu (DeepPoly ReLU relaxation), elementwise over N=16M fp32.
// Outputs concatenated: [x_out | low_out | high_out], each N floats.
// Memory-bound: 192 MiB in + 192 MiB out, touched once -> nontemporal
// loads/stores. float4 16B/lane, grid-stride with 4-way unroll for deeper
// memory-level parallelism (12 independent loads in flight per thread).

#define EPS 1e-7f

typedef float f32x4 __attribute__((ext_vector_type(4)));

__device__ __forceinline__ void relax_one(float X, float L, float H,
                                          float& xo, float& lo, float& ho) {
    xo = fmaxf(X, 0.0f);

    const bool crossing = (L < 0.0f) & (H > 0.0f);
    const bool dead = (H <= 0.0f);

    // Match reference exactly: denom = crossing ? (H-L) : 1.0
    // ub_slope uses denom+EPS, ub_int uses bare denom.
    const float denom = crossing ? (H - L) : 1.0f;
    const float ub_slope = H / (denom + EPS);
    const float ub_int = -(L * H) / denom;
    const float high_cross = ub_slope * H + ub_int;
    // LAMDA = 0 -> low_cross = 0

    ho = crossing ? high_cross : (dead ? 0.0f : H);
    lo = crossing ? 0.0f : (dead ? 0.0f : L);
}

__device__ __forceinline__ void relax_vec(const f32x4& xv, const f32x4& lv,
                                          const f32x4& hv, f32x4& xr,
                                          f32x4& lr, f32x4& hr) {
    float a, b, c;
    relax_one(xv.x, lv.x, hv.x, a, b, c); xr.x = a; lr.x = b; hr.x = c;
    relax_one(xv.y, lv.y, hv.y, a, b, c); xr.y = a; lr.y = b; hr.y = c;
    relax_one(xv.z, lv.z, hv.z, a, b, c); xr.z = a; lr.z = b; hr.z = c;
    relax_one(xv.w, lv.w, hv.w, a, b, c); xr.w = a; lr.w = b; hr.w = c;
}

__global__ void __launch_bounds__(256)
abstract_relu_kernel(const f32x4* __restrict__ x,
                     const f32x4* __restrict__ low,
                     const f32x4* __restrict__ high,
                     f32x4* __restrict__ x_out,
                     f32x4* __restrict__ low_out,
                     f32x4* __restrict__ high_out,
                     int n4) {
    const int stride = gridDim.x * blockDim.x;
    int i = blockIdx.x * blockDim.x + threadIdx.x;

    // 4-way unrolled grid-stride: 12 independent loads in flight.
    for (; i + 3 * stride < n4; i += 4 * stride) {
        const int i0 = i;
        const int i1 = i + stride;
        const int i2 = i + 2 * stride;
        const int i3 = i + 3 * stride;

        const f32x4 xv0 = __builtin_nontemporal_load(&x[i0]);
        const f32x4 lv0 = __builtin_nontemporal_load(&low[i0]);
        const f32x4 hv0 = __builtin_nontemporal_load(&high[i0]);
        const f32x4 xv1 = __builtin_nontemporal_load(&x[i1]);
        const f32x4 lv1 = __builtin_nontemporal_load(&low[i1]);
        const f32x4 hv1 = __builtin_nontemporal_load(&high[i1]);
        const f32x4 xv2 = __builtin_nontemporal_load(&x[i2]);
        const f32x4 lv2 = __builtin_nontemporal_load(&low[i2]);
        const f32x4 hv2 = __builtin_nontemporal_load(&high[i2]);
        const f32x4 xv3 = __builtin_nontemporal_load(&x[i3]);
        const f32x4 lv3 = __builtin_nontemporal_load(&low[i3]);
        const f32x4 hv3 = __builtin_nontemporal_load(&high[i3]);

        f32x4 xr, lr, hr;
        relax_vec(xv0, lv0, hv0, xr, lr, hr);
        __builtin_nontemporal_store(xr, &x_out[i0]);
        __builtin_nontemporal_store(lr, &low_out[i0]);
        __builtin_nontemporal_store(hr, &high_out[i0]);
        relax_vec(xv1, lv1, hv1, xr, lr, hr);
        __builtin_nontemporal_store(xr, &x_out[i1]);
        __builtin_nontemporal_store(lr, &low_out[i1]);
        __builtin_nontemporal_store(hr, &high_out[i1]);
        relax_vec(xv2, lv2, hv2, xr, lr, hr);
        __builtin_nontemporal_store(xr, &x_out[i2]);
        __builtin_nontemporal_store(lr, &low_out[i2]);
        __builtin_nontemporal_store(hr, &high_out[i2]);
        relax_vec(xv3, lv3, hv3, xr, lr, hr);
        __builtin_nontemporal_store(xr, &x_out[i3]);
        __builtin_nontemporal_store(lr, &low_out[i3]);
        __builtin_nontemporal_store(hr, &high_out[i3]);
    }
    // tail
    for (; i < n4; i += stride) {
        const f32x4 xv = __builtin_nontemporal_load(&x[i]);
        const f32x4 lv = __builtin_nontemporal_load(&low[i]);
        const f32x4 hv = __builtin_nontemporal_load(&high[i]);
        f32x4 xr, lr, hr;
        relax_vec(xv, lv, hv, xr, lr, hr);
        __builtin_nontemporal_store(xr, &x_out[i]);
        __builtin_nontemporal_store(lr, &low_out[i]);
        __builtin_nontemporal_store(hr, &high_out[i]);
    }
}

extern "C" void kernel_launch(void* const* d_in, const int* in_sizes, int n_in,
                              void* d_out, int out_size, void* d_ws, size_t ws_size,
                              hipStream_t stream) {
    const int n = in_sizes[0];          // 16777216
    const int n4 = n / 4;               // divisible by 4

    const f32x4* x    = (const f32x4*)d_in[0];
    const f32x4* low  = (const f32x4*)d_in[1];
    const f32x4* high = (const f32x4*)d_in[2];

    float* out = (float*)d_out;
    f32x4* x_out    = (f32x4*)(out);
    f32x4* low_out  = (f32x4*)(out + (size_t)n);
    f32x4* high_out = (f32x4*)(out + 2 * (size_t)n);

    const int block = 256;
    int grid = (n4 + block - 1) / block;
    if (grid > 2048) grid = 2048;       // grid-stride the rest

    abstract_relu_kernel<<<grid, block, 0, stream>>>(x, low, high,
                                                     x_out, low_out, high_out, n4);
}

// Round 4
// 72.152 us; speedup vs baseline: 1.1160x; 1.1160x over previous
//
#include <hip/hip_runtime.h>

// AbstractRelu (DeepPoly ReLU relaxation), elementwise over N=16M fp32.
// Outputs concatenated: [x_out | low_out | high_out], each N floats.
// Memory-bound: 192 MiB in + 192 MiB out, touched once.
// Exact-map structure: ONE float4 triple per thread, no loop — mirrors the
// 7 TB/s fillBuffer kernel: minimal per-wave state, latency hidden by TLP
// (fresh waves replace retired ones), each wave reads 3 contiguous 4KB spans.

#define EPS 1e-7f

typedef float f32x4 __attribute__((ext_vector_type(4)));

__device__ __forceinline__ void relax_one(float X, float L, float H,
                                          float& xo, float& lo, float& ho) {
    xo = fmaxf(X, 0.0f);

    const bool crossing = (L < 0.0f) & (H > 0.0f);
    const bool dead = (H <= 0.0f);

    // Match reference exactly: denom = crossing ? (H-L) : 1.0
    // ub_slope uses denom+EPS, ub_int uses bare denom.
    const float denom = crossing ? (H - L) : 1.0f;
    const float ub_slope = H / (denom + EPS);
    const float ub_int = -(L * H) / denom;
    const float high_cross = ub_slope * H + ub_int;
    // LAMDA = 0 -> low_cross = 0

    ho = crossing ? high_cross : (dead ? 0.0f : H);
    lo = crossing ? 0.0f : (dead ? 0.0f : L);
}

__device__ __forceinline__ void relax_vec(const f32x4& xv, const f32x4& lv,
                                          const f32x4& hv, f32x4& xr,
                                          f32x4& lr, f32x4& hr) {
    float a, b, c;
    relax_one(xv.x, lv.x, hv.x, a, b, c); xr.x = a; lr.x = b; hr.x = c;
    relax_one(xv.y, lv.y, hv.y, a, b, c); xr.y = a; lr.y = b; hr.y = c;
    relax_one(xv.z, lv.z, hv.z, a, b, c); xr.z = a; lr.z = b; hr.z = c;
    relax_one(xv.w, lv.w, hv.w, a, b, c); xr.w = a; lr.w = b; hr.w = c;
}

__global__ void __launch_bounds__(256)
abstract_relu_kernel(const f32x4* __restrict__ x,
                     const f32x4* __restrict__ low,
                     const f32x4* __restrict__ high,
                     f32x4* __restrict__ x_out,
                     f32x4* __restrict__ low_out,
                     f32x4* __restrict__ high_out) {
    const int i = blockIdx.x * blockDim.x + threadIdx.x;  // grid sized exactly

    const f32x4 xv = __builtin_nontemporal_load(&x[i]);
    const f32x4 lv = __builtin_nontemporal_load(&low[i]);
    const f32x4 hv = __builtin_nontemporal_load(&high[i]);

    f32x4 xr, lr, hr;
    relax_vec(xv, lv, hv, xr, lr, hr);

    __builtin_nontemporal_store(xr, &x_out[i]);
    __builtin_nontemporal_store(lr, &low_out[i]);
    __builtin_nontemporal_store(hr, &high_out[i]);
}

extern "C" void kernel_launch(void* const* d_in, const int* in_sizes, int n_in,
                              void* d_out, int out_size, void* d_ws, size_t ws_size,
                              hipStream_t stream) {
    const int n = in_sizes[0];          // 16777216
    const int n4 = n / 4;               // 4194304, divisible by 256

    const f32x4* x    = (const f32x4*)d_in[0];
    const f32x4* low  = (const f32x4*)d_in[1];
    const f32x4* high = (const f32x4*)d_in[2];

    float* out = (float*)d_out;
    f32x4* x_out    = (f32x4*)(out);
    f32x4* low_out  = (f32x4*)(out + (size_t)n);
    f32x4* high_out = (f32x4*)(out + 2 * (size_t)n);

    const int block = 256;
    const int grid = n4 / block;        // 16384 blocks, exact map

    abstract_relu_kernel<<<grid, block, 0, stream>>>(x, low, high,
                                                     x_out, low_out, high_out);
}